// Round 4
// baseline (9413.272 us; speedup 1.0000x reference)
//
#include <hip/hip_runtime.h>

#define B_    128
#define TPAST 1024
#define FN    512
#define TT    1536
#define INF   64
#define IPF   128
#define HD    256
#define NG    1024
#define OUTF  64

typedef _Float16 f16;
typedef _Float16 f16x8 __attribute__((ext_vector_type(8)));
typedef _Float16 f16x4 __attribute__((ext_vector_type(4)));
typedef float    f32x4 __attribute__((ext_vector_type(4)));

__device__ __forceinline__ float sigm_(float x)  { return 1.f / (1.f + __expf(-x)); }
__device__ __forceinline__ float tanh_(float x)  { return 1.f - 2.f / (1.f + __expf(2.f * x)); }

// ---------------------------------------------------------------------------
// prep: fold encoder into past-input weights; fold future encoder into the
// future recurrent matrix; build broadcast future-bias P-block; f16 weights.
// ---------------------------------------------------------------------------
extern "C" __global__ void eprep(
    const float* __restrict__ enc_W, const float* __restrict__ enc_b,
    const float* __restrict__ fut_W, const float* __restrict__ fut_b,
    const float* __restrict__ dec_W,
    const float* __restrict__ pW_ih, const float* __restrict__ pW_hh,
    const float* __restrict__ pb_ih, const float* __restrict__ pb_hh,
    const float* __restrict__ fW_ih, const float* __restrict__ fW_hh,
    const float* __restrict__ fb_ih, const float* __restrict__ fb_hh,
    f16* __restrict__ Wp_in, float* __restrict__ bp,
    f16* __restrict__ Wp16, f16* __restrict__ Wf16,
    f16* __restrict__ Pfut, f16* __restrict__ dW16)
{
  int stride = gridDim.x * blockDim.x;
  int gid = blockIdx.x * blockDim.x + threadIdx.x;
  // Wf = fW_hh + fW_ih @ fut_W   [1024,256];  Wp16 = (f16)pW_hh
  for (int i = gid; i < NG * HD; i += stride) {
    int n = i >> 8, j = i & 255;
    float s = fW_hh[i];
    for (int m = 0; m < IPF; ++m) s += fW_ih[n * IPF + m] * fut_W[m * HD + j];
    Wf16[i] = (f16)s;
    Wp16[i] = (f16)pW_hh[i];
  }
  // Wp_in = pW_ih @ enc_W   [1024,64]
  for (int i = gid; i < NG * INF; i += stride) {
    int n = i >> 6, k = i & 63;
    float s = 0.f;
    for (int m = 0; m < IPF; ++m) s += pW_ih[n * IPF + m] * enc_W[m * INF + k];
    Wp_in[i] = (f16)s;
  }
  for (int i = gid; i < OUTF * HD; i += stride) dW16[i] = (f16)dec_W[i];
  // bp = pW_ih@enc_b + pb_ih + pb_hh ; Pfut[n][0..15] = fW_ih@fut_b + fb_ih + fb_hh
  for (int n = gid; n < NG; n += stride) {
    float s1 = pb_ih[n] + pb_hh[n], s2 = fb_ih[n] + fb_hh[n];
    for (int m = 0; m < IPF; ++m) {
      s1 += pW_ih[n * IPF + m] * enc_b[m];
      s2 += fW_ih[n * IPF + m] * fut_b[m];
    }
    bp[n] = s1;
    f16 v = (f16)s2;
    for (int b = 0; b < 16; ++b) Pfut[n * 16 + b] = v;
  }
}

// ---------------------------------------------------------------------------
// P GEMM: P = x @ Wp_in^T + bp, stored PER-WG CONTIGUOUS:
//   P[((bt*Tc + tl)*NG + n)*16 + blocal]
// ---------------------------------------------------------------------------
extern "C" __global__ __launch_bounds__(64) void epgemm(
    const float* __restrict__ x, const f16* __restrict__ Wp_in,
    const float* __restrict__ bp, f16* __restrict__ P, int t0, int Tc)
{
  int wg = blockIdx.x;
  int tl = wg >> 3, bt = wg & 7;
  int t = t0 + tl;
  int l = (int)threadIdx.x, r = l & 15, g = l >> 4;
  const float* xb = x + ((size_t)(bt * 16 + r) * TPAST + t) * INF;
  f16x8 a[2];
#pragma unroll
  for (int kk = 0; kk < 2; ++kk) {
    const float* px = xb + kk * 32 + g * 8;
    f32x4 v0 = *(const f32x4*)px;
    f32x4 v1 = *(const f32x4*)(px + 4);
#pragma unroll
    for (int e = 0; e < 4; ++e) { a[kk][e] = (f16)v0[e]; a[kk][4 + e] = (f16)v1[e]; }
  }
  f16* Pt = P + ((size_t)bt * Tc + tl) * (NG * 16);
  for (int nt = 0; nt < 64; ++nt) {
    int n = nt * 16 + r;
    f16x8 b0 = *(const f16x8*)(Wp_in + (size_t)n * INF + g * 8);
    f16x8 b1 = *(const f16x8*)(Wp_in + (size_t)n * INF + 32 + g * 8);
    f32x4 acc = {0.f, 0.f, 0.f, 0.f};
    acc = __builtin_amdgcn_mfma_f32_16x16x32_f16(a[0], b0, acc, 0, 0, 0);
    acc = __builtin_amdgcn_mfma_f32_16x16x32_f16(a[1], b1, acc, 0, 0, 0);
    float bias = bp[n];
    f16x4 hv;
#pragma unroll
    for (int e = 0; e < 4; ++e) hv[e] = (f16)(acc[e] + bias);
    *(f16x4*)(Pt + n * 16 + 4 * g) = hv;
  }
}

// ---------------------------------------------------------------------------
// Persistent recurrent kernel. 8 WGs x 512 threads (8 waves, 2 waves/SIMD).
// amdgpu_waves_per_eu(2,2) pins the allocator at 2 waves/EU -> 256-VGPR
// budget so the 192-VGPR weight fragments stay register-resident (round-3
// report of VGPR_Count=128 proved they were being evicted to scratch/L2).
// Weights: kt0..5 in regs, kt6..7 in swizzled LDS (128 KB).
// h (f16, swizzled) + c (f32, stride-20 padded: 8 lanes cover all 32 banks).
// ---------------------------------------------------------------------------
extern "C" __global__ __launch_bounds__(512)
__attribute__((amdgpu_waves_per_eu(2, 2)))
void erecur(
    const f16* __restrict__ W, const f16* __restrict__ P, int pstep,
    f16* __restrict__ hs, f16* __restrict__ h_state, float* __restrict__ c_state,
    int Tc, int init_state)
{
  __shared__ f16  Wl[NG * 64];      // 128 KB : W[:, 192:256], swizzled
  __shared__ f16  hb[16 * HD];      //   8 KB : h[b][j], swizzled by b
  __shared__ float cb[HD * 20];     //  20 KB : c[j][b], padded stride 20

  int tid = (int)threadIdx.x;
  int w = tid >> 6, l = tid & 63, r = l & 15, g = l >> 4;
  int b0 = blockIdx.x * 16;

  // LDS-resident W slice (k = 192..255 for all n)
  for (int nn = tid; nn < NG; nn += 512) {
#pragma unroll
    for (int c8 = 0; c8 < 8; ++c8) {
      f16x8 v = *(const f16x8*)(W + (size_t)nn * HD + 192 + c8 * 8);
      *(f16x8*)&Wl[(nn * 64 + c8 * 8) ^ ((nn & 7) << 3)] = v;
    }
  }
  // Register-resident B-fragments: wave w owns cols [ga*256 + w*32, +32)
  f16x8 wf[4][2][6];
#pragma unroll
  for (int ga = 0; ga < 4; ++ga)
#pragma unroll
    for (int s = 0; s < 2; ++s) {
      int n = ga * 256 + w * 32 + s * 16 + r;
#pragma unroll
      for (int kt = 0; kt < 6; ++kt)
        wf[ga][s][kt] = *(const f16x8*)(W + (size_t)n * HD + kt * 32 + g * 8);
    }
  if (init_state) {
    for (int i = tid; i < 16 * HD; i += 512) hb[i ^ (((i >> 8) & 7) << 3)] = (f16)0.f;
    for (int i = tid; i < HD * 20; i += 512) cb[i] = 0.f;
  } else {
    for (int i = tid; i < 16 * HD; i += 512) {
      int b = i >> 8, j = i & 255;
      hb[i ^ ((b & 7) << 3)] = h_state[(size_t)(b0 + b) * HD + j];
      cb[j * 20 + b] = c_state[(size_t)(b0 + b) * HD + j];
    }
  }
  __syncthreads();

  const f16* Pw = P + (size_t)blockIdx.x * Tc * pstep;
  const f32x4 zero4 = {0.f, 0.f, 0.f, 0.f};

  for (int tl = 0; tl < Tc; ++tl) {
    // issue P loads first: full-GEMM latency cover, consumed after barrier
    f16x4 pv[4][2];
#pragma unroll
    for (int ga = 0; ga < 4; ++ga)
#pragma unroll
      for (int s = 0; s < 2; ++s) {
        int n = ga * 256 + w * 32 + s * 16 + r;
        pv[ga][s] = *(const f16x4*)(Pw + n * 16 + 4 * g);
      }

    f32x4 acc[4][2];
#pragma unroll
    for (int ga = 0; ga < 4; ++ga)
#pragma unroll
      for (int s = 0; s < 2; ++s) acc[ga][s] = zero4;

    // k-tiles 0..5: weights from registers
#pragma unroll
    for (int kt = 0; kt < 6; ++kt) {
      f16x8 a = *(const f16x8*)&hb[(r * HD + kt * 32 + g * 8) ^ ((r & 7) << 3)];
#pragma unroll
      for (int ga = 0; ga < 4; ++ga)
#pragma unroll
        for (int s = 0; s < 2; ++s)
          acc[ga][s] = __builtin_amdgcn_mfma_f32_16x16x32_f16(a, wf[ga][s][kt], acc[ga][s], 0, 0, 0);
    }
    // k-tiles 6..7: weights from swizzled LDS
#pragma unroll
    for (int kt = 6; kt < 8; ++kt) {
      f16x8 a = *(const f16x8*)&hb[(r * HD + kt * 32 + g * 8) ^ ((r & 7) << 3)];
#pragma unroll
      for (int ga = 0; ga < 4; ++ga)
#pragma unroll
        for (int s = 0; s < 2; ++s) {
          int n = ga * 256 + w * 32 + s * 16 + r;
          f16x8 bw = *(const f16x8*)&Wl[(n * 64 + (kt - 6) * 32 + g * 8) ^ ((n & 7) << 3)];
          acc[ga][s] = __builtin_amdgcn_mfma_f32_16x16x32_f16(a, bw, acc[ga][s], 0, 0, 0);
        }
    }
    __syncthreads();  // all h reads done before h is overwritten

#pragma unroll
    for (int s = 0; s < 2; ++s) {
      int j = w * 32 + s * 16 + r;
      f32x4 cold = *(f32x4*)&cb[j * 20 + 4 * g];
      f32x4 cnew;
      f16 hh[4];
#pragma unroll
      for (int e = 0; e < 4; ++e) {
        float xi = acc[0][s][e] + (float)pv[0][s][e];
        float xf = acc[1][s][e] + (float)pv[1][s][e];
        float xg = acc[2][s][e] + (float)pv[2][s][e];
        float xo = acc[3][s][e] + (float)pv[3][s][e];
        float ii = sigm_(xi), ff = sigm_(xf), oo = sigm_(xo), gg = tanh_(xg);
        float cn = ff * cold[e] + ii * gg;
        cnew[e] = cn;
        hh[e] = (f16)(oo * tanh_(cn));
      }
      *(f32x4*)&cb[j * 20 + 4 * g] = cnew;
#pragma unroll
      for (int e = 0; e < 4; ++e) {
        int b = 4 * g + e;
        hb[(b * HD + j) ^ ((b & 7) << 3)] = hh[e];
        hs[((size_t)tl * B_ + b0 + b) * HD + j] = hh[e];
      }
    }
    __syncthreads();
    Pw += pstep;
  }
  // persist state for the next phase/chunk
  for (int i = tid; i < 16 * HD; i += 512) {
    int b = i >> 8, j = i & 255;
    h_state[(size_t)(b0 + b) * HD + j] = hb[i ^ ((b & 7) << 3)];
    c_state[(size_t)(b0 + b) * HD + j] = cb[j * 20 + b];
  }
}

// ---------------------------------------------------------------------------
// Decoder GEMM: out[b][t][o] = hs[t][b][:] @ dec_W^T + dec_b.
// ---------------------------------------------------------------------------
extern "C" __global__ __launch_bounds__(64) void edec(
    const f16* __restrict__ hs, const f16* __restrict__ dW,
    const float* __restrict__ dec_b, float* __restrict__ out, int t0, int Tc)
{
  int wg = blockIdx.x;
  int tt = wg >> 7, b = wg & 127;
  int l = (int)threadIdx.x, r = l & 15, g = l >> 4;
  f16x8 wfr[4][8];
#pragma unroll
  for (int nt = 0; nt < 4; ++nt)
#pragma unroll
    for (int kt = 0; kt < 8; ++kt)
      wfr[nt][kt] = *(const f16x8*)(dW + (size_t)(nt * 16 + r) * HD + kt * 32 + g * 8);
  float bb[4];
#pragma unroll
  for (int nt = 0; nt < 4; ++nt) bb[nt] = dec_b[nt * 16 + r];
  f32x4 acc[2][4];
  const f32x4 zero4 = {0.f, 0.f, 0.f, 0.f};
#pragma unroll
  for (int mt = 0; mt < 2; ++mt)
#pragma unroll
    for (int nt = 0; nt < 4; ++nt) acc[mt][nt] = zero4;
#pragma unroll
  for (int mt = 0; mt < 2; ++mt)
#pragma unroll
    for (int kt = 0; kt < 8; ++kt) {
      f16x8 a = *(const f16x8*)(hs + ((size_t)(tt * 32 + mt * 16 + r) * B_ + b) * HD + kt * 32 + g * 8);
#pragma unroll
      for (int nt = 0; nt < 4; ++nt)
        acc[mt][nt] = __builtin_amdgcn_mfma_f32_16x16x32_f16(a, wfr[nt][kt], acc[mt][nt], 0, 0, 0);
    }
#pragma unroll
  for (int mt = 0; mt < 2; ++mt)
#pragma unroll
    for (int nt = 0; nt < 4; ++nt)
#pragma unroll
      for (int e = 0; e < 4; ++e) {
        int t = t0 + tt * 32 + mt * 16 + 4 * g + e;
        out[((size_t)b * TT + t) * OUTF + nt * 16 + r] = acc[mt][nt][e] + bb[nt];
      }
}

// ---------------------------------------------------------------------------
extern "C" void kernel_launch(void* const* d_in, const int* in_sizes, int n_in,
                              void* d_out, int out_size, void* d_ws, size_t ws_size,
                              hipStream_t stream)
{
  const float* x     = (const float*)d_in[0];
  // d_in[1] = future_n (constant 512)
  const float* enc_W = (const float*)d_in[2];
  const float* enc_b = (const float*)d_in[3];
  const float* fut_W = (const float*)d_in[4];
  const float* fut_b = (const float*)d_in[5];
  const float* dec_W = (const float*)d_in[6];
  const float* dec_b = (const float*)d_in[7];
  const float* pW_ih = (const float*)d_in[8];
  const float* pW_hh = (const float*)d_in[9];
  const float* pb_ih = (const float*)d_in[10];
  const float* pb_hh = (const float*)d_in[11];
  const float* fW_ih = (const float*)d_in[12];
  const float* fW_hh = (const float*)d_in[13];
  const float* fb_ih = (const float*)d_in[14];
  const float* fb_hh = (const float*)d_in[15];
  (void)in_sizes; (void)n_in; (void)out_size;

  char* p = (char*)d_ws;
  auto alloc = [&](size_t bytes) { char* q = p; p += (bytes + 255) & ~(size_t)255; return q; };
  f16*   Wp_in = (f16*)  alloc((size_t)NG * INF * 2);
  float* bp    = (float*)alloc((size_t)NG * 4);
  f16*   Wp16  = (f16*)  alloc((size_t)NG * HD * 2);
  f16*   Wf16  = (f16*)  alloc((size_t)NG * HD * 2);
  f16*   Pfut  = (f16*)  alloc((size_t)NG * 16 * 2);
  f16*   dW16  = (f16*)  alloc((size_t)OUTF * HD * 2);
  f16*   h_st  = (f16*)  alloc((size_t)B_ * HD * 2);
  float* c_st  = (float*)alloc((size_t)B_ * HD * 4);
  size_t fixed = (size_t)(p - (char*)d_ws);

  auto need = [&](int rr) {
    size_t pp = (size_t)(rr < TPAST ? rr : TPAST) * NG * B_ * 2;
    size_t hh = (size_t)rr * B_ * HD * 2;
    return pp + hh + 4096;
  };
  size_t avail = ws_size > fixed ? ws_size - fixed : 0;
  int R = 128;
  if (avail >= need(1536)) R = 1536;
  else if (avail >= need(512)) R = 512;
  else if (avail >= need(256)) R = 256;

  f16* Pbuf = (f16*)alloc((size_t)(R < TPAST ? R : TPAST) * NG * B_ * 2);
  f16* HS   = (f16*)alloc((size_t)R * B_ * HD * 2);

  eprep<<<512, 256, 0, stream>>>(enc_W, enc_b, fut_W, fut_b, dec_W,
                                 pW_ih, pW_hh, pb_ih, pb_hh,
                                 fW_ih, fW_hh, fb_ih, fb_hh,
                                 Wp_in, bp, Wp16, Wf16, Pfut, dW16);

  // past phase
  for (int t0 = 0; t0 < TPAST; t0 += R) {
    int Tc = (TPAST - t0) < R ? (TPAST - t0) : R;
    epgemm<<<Tc * 8, 64, 0, stream>>>(x, Wp_in, bp, Pbuf, t0, Tc);
    erecur<<<8, 512, 0, stream>>>(Wp16, Pbuf, NG * 16, HS, h_st, c_st, Tc, t0 == 0 ? 1 : 0);
    edec<<<(Tc / 32) * B_, 64, 0, stream>>>(HS, dW16, dec_b, (float*)d_out, t0, Tc);
  }
  // future phase (encoder folded into Wf16; bias via broadcast Pfut, stride 0)
  for (int t0 = TPAST; t0 < TT; t0 += R) {
    int Tc = (TT - t0) < R ? (TT - t0) : R;
    erecur<<<8, 512, 0, stream>>>(Wf16, Pfut, 0, HS, h_st, c_st, Tc, 0);
    edec<<<(Tc / 32) * B_, 64, 0, stream>>>(HS, dW16, dec_b, (float*)d_out, t0, Tc);
  }
}

// Round 5
// 8086.114 us; speedup vs baseline: 1.1641x; 1.1641x over previous
//
#include <hip/hip_runtime.h>

#define B_    128
#define TPAST 1024
#define FN    512
#define TT    1536
#define INF   64
#define IPF   128
#define HD    256
#define NG    1024
#define OUTF  64

typedef _Float16 f16;
typedef _Float16 f16x8 __attribute__((ext_vector_type(8)));
typedef _Float16 f16x4 __attribute__((ext_vector_type(4)));
typedef float    f32x4 __attribute__((ext_vector_type(4)));

__device__ __forceinline__ float sigm_(float x) {
  return __builtin_amdgcn_rcpf(1.f + __expf(-x));
}
__device__ __forceinline__ float tanh_(float x) {
  return 1.f - 2.f * __builtin_amdgcn_rcpf(1.f + __expf(2.f * x));
}
// Opaque 16B load: asm result cannot be rematerialized by the register
// allocator, forcing the loaded weight fragments to stay register-resident
// across the recurrence loop (plain loads were re-issued every step).
__device__ __forceinline__ f16x8 oload16(const f16* p) {
  f16x8 v;
  asm volatile("global_load_dwordx4 %0, %1, off\n\ts_waitcnt vmcnt(0)"
               : "=v"(v) : "v"(p));
  return v;
}

// ---------------------------------------------------------------------------
// prep: fold encoder into past-input weights; fold future encoder into the
// future recurrent matrix; convert weights to f16.
// ---------------------------------------------------------------------------
extern "C" __global__ void eprep(
    const float* __restrict__ enc_W, const float* __restrict__ enc_b,
    const float* __restrict__ fut_W, const float* __restrict__ fut_b,
    const float* __restrict__ dec_W,
    const float* __restrict__ pW_ih, const float* __restrict__ pW_hh,
    const float* __restrict__ pb_ih, const float* __restrict__ pb_hh,
    const float* __restrict__ fW_ih, const float* __restrict__ fW_hh,
    const float* __restrict__ fb_ih, const float* __restrict__ fb_hh,
    f16* __restrict__ Wp_in, float* __restrict__ bp,
    f16* __restrict__ Wp16, f16* __restrict__ Wf16,
    float* __restrict__ bf, f16* __restrict__ dW16)
{
  int stride = gridDim.x * blockDim.x;
  int gid = blockIdx.x * blockDim.x + threadIdx.x;
  // Wf = fW_hh + fW_ih @ fut_W   [1024,256];  Wp16 = (f16)pW_hh
  for (int i = gid; i < NG * HD; i += stride) {
    int n = i >> 8, j = i & 255;
    float s = fW_hh[i];
    for (int m = 0; m < IPF; ++m) s += fW_ih[n * IPF + m] * fut_W[m * HD + j];
    Wf16[i] = (f16)s;
    Wp16[i] = (f16)pW_hh[i];
  }
  // Wp_in = pW_ih @ enc_W   [1024,64]
  for (int i = gid; i < NG * INF; i += stride) {
    int n = i >> 6, k = i & 63;
    float s = 0.f;
    for (int m = 0; m < IPF; ++m) s += pW_ih[n * IPF + m] * enc_W[m * INF + k];
    Wp_in[i] = (f16)s;
  }
  for (int i = gid; i < OUTF * HD; i += stride) dW16[i] = (f16)dec_W[i];
  // bp = pW_ih@enc_b + pb_ih + pb_hh ; bf = fW_ih@fut_b + fb_ih + fb_hh
  for (int n = gid; n < NG; n += stride) {
    float s1 = pb_ih[n] + pb_hh[n], s2 = fb_ih[n] + fb_hh[n];
    for (int m = 0; m < IPF; ++m) {
      s1 += pW_ih[n * IPF + m] * enc_b[m];
      s2 += fW_ih[n * IPF + m] * fut_b[m];
    }
    bp[n] = s1; bf[n] = s2;
  }
}

// ---------------------------------------------------------------------------
// P GEMM: P = x @ Wp_in^T + bp, stored PER-WG CONTIGUOUS:
//   P[((bt*Tc + tl)*NG + n)*16 + blocal]
// ---------------------------------------------------------------------------
extern "C" __global__ __launch_bounds__(64) void epgemm(
    const float* __restrict__ x, const f16* __restrict__ Wp_in,
    const float* __restrict__ bp, f16* __restrict__ P, int t0, int Tc)
{
  int wg = blockIdx.x;
  int tl = wg >> 3, bt = wg & 7;
  int t = t0 + tl;
  int l = (int)threadIdx.x, r = l & 15, g = l >> 4;
  const float* xb = x + ((size_t)(bt * 16 + r) * TPAST + t) * INF;
  f16x8 a[2];
#pragma unroll
  for (int kk = 0; kk < 2; ++kk) {
    const float* px = xb + kk * 32 + g * 8;
    f32x4 v0 = *(const f32x4*)px;
    f32x4 v1 = *(const f32x4*)(px + 4);
#pragma unroll
    for (int e = 0; e < 4; ++e) { a[kk][e] = (f16)v0[e]; a[kk][4 + e] = (f16)v1[e]; }
  }
  f16* Pt = P + ((size_t)bt * Tc + tl) * (NG * 16);
  for (int nt = 0; nt < 64; ++nt) {
    int n = nt * 16 + r;
    f16x8 b0 = *(const f16x8*)(Wp_in + (size_t)n * INF + g * 8);
    f16x8 b1 = *(const f16x8*)(Wp_in + (size_t)n * INF + 32 + g * 8);
    f32x4 acc = {0.f, 0.f, 0.f, 0.f};
    acc = __builtin_amdgcn_mfma_f32_16x16x32_f16(a[0], b0, acc, 0, 0, 0);
    acc = __builtin_amdgcn_mfma_f32_16x16x32_f16(a[1], b1, acc, 0, 0, 0);
    float bias = bp[n];
    f16x4 hv;
#pragma unroll
    for (int e = 0; e < 4; ++e) hv[e] = (f16)(acc[e] + bias);
    *(f16x4*)(Pt + n * 16 + 4 * g) = hv;
  }
}

// ---------------------------------------------------------------------------
// Persistent recurrent kernel. 8 WGs x 512 threads (8 waves, 2 waves/SIMD).
// Weight fragments kt0..5 loaded ONCE via opaque asm loads (register-pinned),
// kt6..7 in swizzled LDS (128 KB). h (f16, swizzled) + c (f32, stride-20
// padded) in LDS. Past phase streams P; future phase folds bias into the
// accumulator init (zero per-step global traffic).
// ---------------------------------------------------------------------------
extern "C" __global__ __launch_bounds__(512)
__attribute__((amdgpu_waves_per_eu(2, 2)))
void erecur(
    const f16* __restrict__ W, const f16* __restrict__ P, int pstep,
    const float* __restrict__ bias,
    f16* __restrict__ hs, f16* __restrict__ h_state, float* __restrict__ c_state,
    int Tc, int init_state)
{
  __shared__ f16  Wl[NG * 64];      // 128 KB : W[:, 192:256], swizzled
  __shared__ f16  hb[16 * HD];      //   8 KB : h[b][j], swizzled by b
  __shared__ float cb[HD * 20];     //  20 KB : c[j][b], padded stride 20

  int tid = (int)threadIdx.x;
  int w = tid >> 6, l = tid & 63, r = l & 15, g = l >> 4;
  int b0 = blockIdx.x * 16;

  // LDS-resident W slice (k = 192..255 for all n)
  for (int nn = tid; nn < NG; nn += 512) {
#pragma unroll
    for (int c8 = 0; c8 < 8; ++c8) {
      f16x8 v = *(const f16x8*)(W + (size_t)nn * HD + 192 + c8 * 8);
      *(f16x8*)&Wl[(nn * 64 + c8 * 8) ^ ((nn & 7) << 3)] = v;
    }
  }
  // Register-pinned B-fragments: wave w owns cols [ga*256 + w*32, +32)
  f16x8 wf[4][2][6];
#pragma unroll
  for (int ga = 0; ga < 4; ++ga)
#pragma unroll
    for (int s = 0; s < 2; ++s) {
      int n = ga * 256 + w * 32 + s * 16 + r;
#pragma unroll
      for (int kt = 0; kt < 6; ++kt)
        wf[ga][s][kt] = oload16(W + (size_t)n * HD + kt * 32 + g * 8);
    }
  // Future phase: per-gate bias held in 8 registers, folded into acc init
  float bi[4][2];
  if (!P) {
#pragma unroll
    for (int ga = 0; ga < 4; ++ga)
#pragma unroll
      for (int s = 0; s < 2; ++s)
        bi[ga][s] = bias[ga * 256 + w * 32 + s * 16 + r];
  }
  if (init_state) {
    for (int i = tid; i < 16 * HD; i += 512) hb[i ^ (((i >> 8) & 7) << 3)] = (f16)0.f;
    for (int i = tid; i < HD * 20; i += 512) cb[i] = 0.f;
  } else {
    for (int i = tid; i < 16 * HD; i += 512) {
      int b = i >> 8, j = i & 255;
      hb[i ^ ((b & 7) << 3)] = h_state[(size_t)(b0 + b) * HD + j];
      cb[j * 20 + b] = c_state[(size_t)(b0 + b) * HD + j];
    }
  }
  __syncthreads();

  const f16* Pw = P ? (P + (size_t)blockIdx.x * Tc * pstep) : nullptr;

  for (int tl = 0; tl < Tc; ++tl) {
    // past phase: issue P loads first (full-GEMM latency cover)
    f16x4 pv[4][2];
    if (P) {
#pragma unroll
      for (int ga = 0; ga < 4; ++ga)
#pragma unroll
        for (int s = 0; s < 2; ++s) {
          int n = ga * 256 + w * 32 + s * 16 + r;
          pv[ga][s] = *(const f16x4*)(Pw + n * 16 + 4 * g);
        }
    }

    f32x4 acc[4][2];
#pragma unroll
    for (int ga = 0; ga < 4; ++ga)
#pragma unroll
      for (int s = 0; s < 2; ++s) {
        float b0i = P ? 0.f : bi[ga][s];
        acc[ga][s][0] = b0i; acc[ga][s][1] = b0i;
        acc[ga][s][2] = b0i; acc[ga][s][3] = b0i;
      }

    // k-tiles 0..5: weights from registers
#pragma unroll
    for (int kt = 0; kt < 6; ++kt) {
      f16x8 a = *(const f16x8*)&hb[(r * HD + kt * 32 + g * 8) ^ ((r & 7) << 3)];
#pragma unroll
      for (int ga = 0; ga < 4; ++ga)
#pragma unroll
        for (int s = 0; s < 2; ++s)
          acc[ga][s] = __builtin_amdgcn_mfma_f32_16x16x32_f16(a, wf[ga][s][kt], acc[ga][s], 0, 0, 0);
    }
    // k-tiles 6..7: weights from swizzled LDS
#pragma unroll
    for (int kt = 6; kt < 8; ++kt) {
      f16x8 a = *(const f16x8*)&hb[(r * HD + kt * 32 + g * 8) ^ ((r & 7) << 3)];
#pragma unroll
      for (int ga = 0; ga < 4; ++ga)
#pragma unroll
        for (int s = 0; s < 2; ++s) {
          int n = ga * 256 + w * 32 + s * 16 + r;
          f16x8 bw = *(const f16x8*)&Wl[(n * 64 + (kt - 6) * 32 + g * 8) ^ ((n & 7) << 3)];
          acc[ga][s] = __builtin_amdgcn_mfma_f32_16x16x32_f16(a, bw, acc[ga][s], 0, 0, 0);
        }
    }
    __syncthreads();  // all h reads done before h is overwritten

#pragma unroll
    for (int s = 0; s < 2; ++s) {
      int j = w * 32 + s * 16 + r;
      f32x4 cold = *(f32x4*)&cb[j * 20 + 4 * g];
      f32x4 cnew;
      f16 hh[4];
#pragma unroll
      for (int e = 0; e < 4; ++e) {
        float xi = acc[0][s][e], xf = acc[1][s][e], xg = acc[2][s][e], xo = acc[3][s][e];
        if (P) {
          xi += (float)pv[0][s][e]; xf += (float)pv[1][s][e];
          xg += (float)pv[2][s][e]; xo += (float)pv[3][s][e];
        }
        float ii = sigm_(xi), ff = sigm_(xf), oo = sigm_(xo), gg = tanh_(xg);
        float cn = ff * cold[e] + ii * gg;
        cnew[e] = cn;
        hh[e] = (f16)(oo * tanh_(cn));
      }
      *(f32x4*)&cb[j * 20 + 4 * g] = cnew;
#pragma unroll
      for (int e = 0; e < 4; ++e) {
        int b = 4 * g + e;
        hb[(b * HD + j) ^ ((b & 7) << 3)] = hh[e];
        hs[((size_t)tl * B_ + b0 + b) * HD + j] = hh[e];
      }
    }
    __syncthreads();
    if (P) Pw += pstep;
  }
  // persist state for the next phase/chunk
  for (int i = tid; i < 16 * HD; i += 512) {
    int b = i >> 8, j = i & 255;
    h_state[(size_t)(b0 + b) * HD + j] = hb[i ^ ((b & 7) << 3)];
    c_state[(size_t)(b0 + b) * HD + j] = cb[j * 20 + b];
  }
}

// ---------------------------------------------------------------------------
// Decoder GEMM: out[b][t][o] = hs[t][b][:] @ dec_W^T + dec_b.
// ---------------------------------------------------------------------------
extern "C" __global__ __launch_bounds__(64) void edec(
    const f16* __restrict__ hs, const f16* __restrict__ dW,
    const float* __restrict__ dec_b, float* __restrict__ out, int t0, int Tc)
{
  int wg = blockIdx.x;
  int tt = wg >> 7, b = wg & 127;
  int l = (int)threadIdx.x, r = l & 15, g = l >> 4;
  f16x8 wfr[4][8];
#pragma unroll
  for (int nt = 0; nt < 4; ++nt)
#pragma unroll
    for (int kt = 0; kt < 8; ++kt)
      wfr[nt][kt] = *(const f16x8*)(dW + (size_t)(nt * 16 + r) * HD + kt * 32 + g * 8);
  float bb[4];
#pragma unroll
  for (int nt = 0; nt < 4; ++nt) bb[nt] = dec_b[nt * 16 + r];
  f32x4 acc[2][4];
  const f32x4 zero4 = {0.f, 0.f, 0.f, 0.f};
#pragma unroll
  for (int mt = 0; mt < 2; ++mt)
#pragma unroll
    for (int nt = 0; nt < 4; ++nt) acc[mt][nt] = zero4;
#pragma unroll
  for (int mt = 0; mt < 2; ++mt)
#pragma unroll
    for (int kt = 0; kt < 8; ++kt) {
      f16x8 a = *(const f16x8*)(hs + ((size_t)(tt * 32 + mt * 16 + r) * B_ + b) * HD + kt * 32 + g * 8);
#pragma unroll
      for (int nt = 0; nt < 4; ++nt)
        acc[mt][nt] = __builtin_amdgcn_mfma_f32_16x16x32_f16(a, wfr[nt][kt], acc[mt][nt], 0, 0, 0);
    }
#pragma unroll
  for (int mt = 0; mt < 2; ++mt)
#pragma unroll
    for (int nt = 0; nt < 4; ++nt)
#pragma unroll
      for (int e = 0; e < 4; ++e) {
        int t = t0 + tt * 32 + mt * 16 + 4 * g + e;
        out[((size_t)b * TT + t) * OUTF + nt * 16 + r] = acc[mt][nt][e] + bb[nt];
      }
}

// ---------------------------------------------------------------------------
extern "C" void kernel_launch(void* const* d_in, const int* in_sizes, int n_in,
                              void* d_out, int out_size, void* d_ws, size_t ws_size,
                              hipStream_t stream)
{
  const float* x     = (const float*)d_in[0];
  // d_in[1] = future_n (constant 512)
  const float* enc_W = (const float*)d_in[2];
  const float* enc_b = (const float*)d_in[3];
  const float* fut_W = (const float*)d_in[4];
  const float* fut_b = (const float*)d_in[5];
  const float* dec_W = (const float*)d_in[6];
  const float* dec_b = (const float*)d_in[7];
  const float* pW_ih = (const float*)d_in[8];
  const float* pW_hh = (const float*)d_in[9];
  const float* pb_ih = (const float*)d_in[10];
  const float* pb_hh = (const float*)d_in[11];
  const float* fW_ih = (const float*)d_in[12];
  const float* fW_hh = (const float*)d_in[13];
  const float* fb_ih = (const float*)d_in[14];
  const float* fb_hh = (const float*)d_in[15];
  (void)in_sizes; (void)n_in; (void)out_size;

  char* p = (char*)d_ws;
  auto alloc = [&](size_t bytes) { char* q = p; p += (bytes + 255) & ~(size_t)255; return q; };
  f16*   Wp_in = (f16*)  alloc((size_t)NG * INF * 2);
  float* bp    = (float*)alloc((size_t)NG * 4);
  f16*   Wp16  = (f16*)  alloc((size_t)NG * HD * 2);
  f16*   Wf16  = (f16*)  alloc((size_t)NG * HD * 2);
  float* bfb   = (float*)alloc((size_t)NG * 4);
  f16*   dW16  = (f16*)  alloc((size_t)OUTF * HD * 2);
  f16*   h_st  = (f16*)  alloc((size_t)B_ * HD * 2);
  float* c_st  = (float*)alloc((size_t)B_ * HD * 4);
  size_t fixed = (size_t)(p - (char*)d_ws);

  auto need = [&](int rr) {
    size_t pp = (size_t)(rr < TPAST ? rr : TPAST) * NG * B_ * 2;
    size_t hh = (size_t)rr * B_ * HD * 2;
    return pp + hh + 4096;
  };
  size_t avail = ws_size > fixed ? ws_size - fixed : 0;
  int R = 128;
  if (avail >= need(1536)) R = 1536;
  else if (avail >= need(512)) R = 512;
  else if (avail >= need(256)) R = 256;

  f16* Pbuf = (f16*)alloc((size_t)(R < TPAST ? R : TPAST) * NG * B_ * 2);
  f16* HS   = (f16*)alloc((size_t)R * B_ * HD * 2);

  eprep<<<512, 256, 0, stream>>>(enc_W, enc_b, fut_W, fut_b, dec_W,
                                 pW_ih, pW_hh, pb_ih, pb_hh,
                                 fW_ih, fW_hh, fb_ih, fb_hh,
                                 Wp_in, bp, Wp16, Wf16, bfb, dW16);

  // past phase
  for (int t0 = 0; t0 < TPAST; t0 += R) {
    int Tc = (TPAST - t0) < R ? (TPAST - t0) : R;
    epgemm<<<Tc * 8, 64, 0, stream>>>(x, Wp_in, bp, Pbuf, t0, Tc);
    erecur<<<8, 512, 0, stream>>>(Wp16, Pbuf, NG * 16, nullptr, HS, h_st, c_st, Tc, t0 == 0 ? 1 : 0);
    edec<<<(Tc / 32) * B_, 64, 0, stream>>>(HS, dW16, dec_b, (float*)d_out, t0, Tc);
  }
  // future phase (encoder folded into Wf16; bias folded into acc init)
  for (int t0 = TPAST; t0 < TT; t0 += R) {
    int Tc = (TT - t0) < R ? (TT - t0) : R;
    erecur<<<8, 512, 0, stream>>>(Wf16, nullptr, 0, bfb, HS, h_st, c_st, Tc, 0);
    edec<<<(Tc / 32) * B_, 64, 0, stream>>>(HS, dW16, dec_b, (float*)d_out, t0, Tc);
  }
}